// Round 14
// baseline (3739.235 us; speedup 1.0000x reference)
//
#include <hip/hip_runtime.h>
#include <hip/hip_cooperative_groups.h>

#define NN 50000
#define TE 48
#define TF 24
#define DEG 32
#define NW 16            // waves per block
#define NPW 16           // nodes per wave
#define NPB 256          // nodes per block
#define NBLK 196         // 196*256 = 50176 >= 50000; co-resident (1 block/CU)

// packed global weight buffer (bytes)
#define F_W0H 0
#define F_W1I 24
#define F_W1H 48
#define F_O1W 72
#define F_GNN 80
#define DENSE_BYTES (88*1024)                 // 90112
#define SP64_OFF DENSE_BYTES
#define SP64_BYTES (36*64*4)                  // 9216
#define W2_OFF (SP64_OFF + SP64_BYTES)        // 99328
#define W2_ELEM (W2_OFF/2)
#define EXTRA_OFF (W2_OFF + 4096)             // 103424: f32 b2[32], wo[32], o2w[64]
#define GBUF_BYTES (EXTRA_OFF + 512)          // 103936

// LDS: [0, EXTRA_OFF) = dense + sp64 + W2, then XT, then wave scratch
#define L_XT_OFF EXTRA_OFF                    // 103424
#define L_SCR_OFF (L_XT_OFF + 512)            // 103936
#define WAVE_SCR 2048
#define LDS_TOTAL (L_SCR_OFF + NW*WAVE_SCR)   // 136704

typedef _Float16 f16;
typedef __attribute__((ext_vector_type(8))) _Float16 f16x8;
typedef __attribute__((ext_vector_type(2))) __fp16 fp16x2_builtin;
typedef __attribute__((ext_vector_type(4))) float f32x4;

__device__ __forceinline__ float frcp(float x) { return __builtin_amdgcn_rcpf(x); }
__device__ __forceinline__ float sigf(float x) { return frcp(1.f + __expf(-x)); }
__device__ __forceinline__ float tanhfast(float x) {
    float e = __expf(-2.f * fabsf(x));
    float r = (1.f - e) * frcp(1.f + e);
    return copysignf(r, x);
}
__device__ __forceinline__ f32x4 mf(f16x8 a, f16x8 b, f32x4 c) {
    return __builtin_amdgcn_mfma_f32_16x16x32_f16(a, b, c, 0, 0, 0);
}
__device__ __forceinline__ f16x8 ldfrag(const char* L, int f, int l) {
    return *(const f16x8*)(L + f * 1024 + l * 16);
}
__device__ __forceinline__ f16x8 spfrag64(const unsigned* sp, int tt, int l) {
    unsigned d = sp[tt * 64 + l];     // zero for lanes >=16 (table padded)
    union { unsigned u; f16 h[2]; } c; c.u = d;
    f16x8 r = {};
    r[0] = c.h[0]; r[1] = c.h[1];
    return r;
}
__device__ __forceinline__ unsigned pk2(float a, float b) {
    fp16x2_builtin t = __builtin_amdgcn_cvt_pkrtz(a, b);
    union { fp16x2_builtin v; unsigned u; } c; c.v = t; return c.u;
}
__device__ __forceinline__ void upk2(unsigned u, float& a, float& b) {
    union { unsigned uu; f16 h[2]; } c; c.uu = u;
    a = (float)c.h[0]; b = (float)c.h[1];
}

struct Wctx {
    int l, g, n;
    char* S;
    const char* WL;
    const unsigned* SP;
    const float* XT;
};

// packed h (uint2[4], D-layout) -> B-frag via wave-internal LDS scratch
__device__ __forceinline__ void transp(const Wctx& W, const uint2 (&hp)[4], f16x8 (&hB)[2]) {
    #pragma unroll
    for (int nt = 0; nt < 4; ++nt)
        *(uint2*)(W.S + W.n * 128 + (((2 * nt + (W.g >> 1)) ^ (W.n & 7)) * 16) + 8 * (W.g & 1)) = hp[nt];
    #pragma unroll
    for (int s = 0; s < 2; ++s)
        hB[s] = *(const f16x8*)(W.S + W.n * 128 + (((4 * s + W.g) ^ (W.n & 7)) * 16));
}

// ---- GRU sub-phases ----
__device__ __forceinline__ void gru_l0(const Wctx& W, f16x8 xb,
    const f16x8 (&h0B)[2], uint2 (&h0p)[4])
{
    const f32x4 z4 = {0.f, 0.f, 0.f, 0.f};
    const int l = W.l;
    #pragma unroll
    for (int nt = 0; nt < 4; ++nt) {
        f32x4 aR = mf(spfrag64(W.SP, nt, l), xb, z4);
        aR = mf(ldfrag(W.WL, F_W0H + nt * 2,     l), h0B[0], aR);
        aR = mf(ldfrag(W.WL, F_W0H + nt * 2 + 1, l), h0B[1], aR);
        f32x4 aZ = mf(spfrag64(W.SP, 4 + nt, l), xb, z4);
        aZ = mf(ldfrag(W.WL, F_W0H + (4 + nt) * 2,     l), h0B[0], aZ);
        aZ = mf(ldfrag(W.WL, F_W0H + (4 + nt) * 2 + 1, l), h0B[1], aZ);
        f32x4 aNi = mf(spfrag64(W.SP, 8 + nt, l), xb, z4);
        f32x4 aNh = mf(spfrag64(W.SP, 12 + nt, l), xb, z4);
        aNh = mf(ldfrag(W.WL, F_W0H + (8 + nt) * 2,     l), h0B[0], aNh);
        aNh = mf(ldfrag(W.WL, F_W0H + (8 + nt) * 2 + 1, l), h0B[1], aNh);
        float ho[4], hn[4];
        upk2(h0p[nt].x, ho[0], ho[1]);
        upk2(h0p[nt].y, ho[2], ho[3]);
        #pragma unroll
        for (int r = 0; r < 4; ++r) {
            float rg = sigf(aR[r]);
            float zg = sigf(aZ[r]);
            float ng = tanhfast(aNi[r] + rg * aNh[r]);
            hn[r] = ng + zg * (ho[r] - ng);
        }
        h0p[nt].x = pk2(hn[0], hn[1]);
        h0p[nt].y = pk2(hn[2], hn[3]);
    }
}

template<int NT0, int NT1>
__device__ __forceinline__ void gru_l1(const Wctx& W, f16x8 xb,
    const f16x8 (&h0B)[2], const f16x8 (&h1B)[2], uint2 (&h1p)[4])
{
    const f32x4 z4 = {0.f, 0.f, 0.f, 0.f};
    const int l = W.l;
    #pragma unroll
    for (int nt = NT0; nt < NT1; ++nt) {
        f32x4 aRa = mf(spfrag64(W.SP, 16 + nt, l), xb, z4);
        aRa = mf(ldfrag(W.WL, F_W1I + nt * 2,     l), h0B[0], aRa);
        aRa = mf(ldfrag(W.WL, F_W1I + nt * 2 + 1, l), h0B[1], aRa);
        f32x4 aRb = mf(ldfrag(W.WL, F_W1H + nt * 2, l), h1B[0], z4);
        aRb = mf(ldfrag(W.WL, F_W1H + nt * 2 + 1,   l), h1B[1], aRb);
        f32x4 aZa = mf(spfrag64(W.SP, 20 + nt, l), xb, z4);
        aZa = mf(ldfrag(W.WL, F_W1I + (4 + nt) * 2,     l), h0B[0], aZa);
        aZa = mf(ldfrag(W.WL, F_W1I + (4 + nt) * 2 + 1, l), h0B[1], aZa);
        f32x4 aZb = mf(ldfrag(W.WL, F_W1H + (4 + nt) * 2, l), h1B[0], z4);
        aZb = mf(ldfrag(W.WL, F_W1H + (4 + nt) * 2 + 1,   l), h1B[1], aZb);
        f32x4 aNi = mf(spfrag64(W.SP, 24 + nt, l), xb, z4);
        aNi = mf(ldfrag(W.WL, F_W1I + (8 + nt) * 2,     l), h0B[0], aNi);
        aNi = mf(ldfrag(W.WL, F_W1I + (8 + nt) * 2 + 1, l), h0B[1], aNi);
        f32x4 aNh = mf(spfrag64(W.SP, 28 + nt, l), xb, z4);
        aNh = mf(ldfrag(W.WL, F_W1H + (8 + nt) * 2,     l), h1B[0], aNh);
        aNh = mf(ldfrag(W.WL, F_W1H + (8 + nt) * 2 + 1, l), h1B[1], aNh);
        float ho[4], hn[4];
        upk2(h1p[nt].x, ho[0], ho[1]);
        upk2(h1p[nt].y, ho[2], ho[3]);
        #pragma unroll
        for (int r = 0; r < 4; ++r) {
            float rg = sigf(aRa[r] + aRb[r]);
            float zg = sigf(aZa[r] + aZb[r]);
            float ng = tanhfast(aNi[r] + rg * aNh[r]);
            hn[r] = ng + zg * (ho[r] - ng);
        }
        h1p[nt].x = pk2(hn[0], hn[1]);
        h1p[nt].y = pk2(hn[2], hn[3]);
    }
}

__device__ __forceinline__ float gru_head(const Wctx& W, f16x8 xb, const f16x8 (&h1B)[2])
{
    const f32x4 z4 = {0.f, 0.f, 0.f, 0.f};
    const int l = W.l;
    float y = 0.f;
    #pragma unroll
    for (int nt = 0; nt < 4; ++nt) {
        f32x4 aH = mf(spfrag64(W.SP, 32 + nt, l), xb, z4);
        aH = mf(ldfrag(W.WL, F_O1W + nt * 2,     l), h1B[0], aH);
        aH = mf(ldfrag(W.WL, F_O1W + nt * 2 + 1, l), h1B[1], aH);
        f32x4 ow = *(const f32x4*)(W.XT + 64 + nt * 16 + W.g * 4);
        #pragma unroll
        for (int r = 0; r < 4; ++r)
            y += fmaxf(aH[r], 0.f) * ow[r];
    }
    y += __shfl_xor(y, 16, 64);
    y += __shfl_xor(y, 32, 64);
    return y;
}

// monolithic step
__device__ __forceinline__ float gru16_step(const Wctx& W, float x,
    f16x8 (&h0B)[2], f16x8 (&h1B)[2], uint2 (&h0p)[4], uint2 (&h1p)[4])
{
    f16x8 xb = {};
    if (W.g == 0) { xb[0] = (f16)x; xb[1] = (f16)1.0f; }
    gru_l0(W, xb, h0B, h0p);
    transp(W, h0p, h0B);
    gru_l1<0, 4>(W, xb, h0B, h1B, h1p);
    transp(W, h1p, h1B);
    return gru_head(W, xb, h1B);
}

__device__ __forceinline__ float gru16_step_p(const Wctx& W, float x,
    uint2 (&h0p)[4], uint2 (&h1p)[4])
{
    f16x8 h0B[2], h1B[2];
    transp(W, h0p, h0B);
    transp(W, h1p, h1B);
    return gru16_step(W, x, h0B, h1B, h0p, h1p);
}

__device__ __forceinline__ void stage_all(char* smem, const f16* wfrag, int tid) {
    uint4* d = (uint4*)smem;
    const uint4* s4 = (const uint4*)wfrag;
    for (int i = tid; i < EXTRA_OFF / 16; i += 1024) d[i] = s4[i];
    if (tid < 32) {
        uint4* de = (uint4*)(smem + L_XT_OFF);
        const uint4* se = (const uint4*)((const char*)wfrag + EXTRA_OFF);
        de[tid] = se[tid];
    }
    __syncthreads();
}

// ---------------- weight packing ----------------
__global__ __launch_bounds__(256)
void pack_weights(const float* __restrict__ w0i, const float* __restrict__ w0h,
                  const float* __restrict__ b0i, const float* __restrict__ b0h,
                  const float* __restrict__ w1i, const float* __restrict__ w1h,
                  const float* __restrict__ b1i, const float* __restrict__ b1h,
                  const float* __restrict__ o1w, const float* __restrict__ o1b,
                  const float* __restrict__ gw1, const float* __restrict__ gb1,
                  const float* __restrict__ gw2, const float* __restrict__ gb2,
                  const float* __restrict__ gwo, const float* __restrict__ o2w,
                  f16* __restrict__ wf)
{
    const int i = blockIdx.x * 256 + threadIdx.x;
    if (i < 92 * 64) {
        const int f = i >> 6, l = i & 63;
        const int lr = l & 15, g = l >> 4;
        f16x8 out = {};
        if (f < F_GNN) {
            const float* src; int fb;
            if (f < F_W1I)      { src = w0h; fb = f; }
            else if (f < F_W1H) { src = w1i; fb = f - F_W1I; }
            else if (f < F_O1W) { src = w1h; fb = f - F_W1H; }
            else                { src = o1w; fb = f - F_O1W; }
            const int nt = fb >> 1, s = fb & 1;
            const int row = nt * 16 + lr, k0 = s * 32 + g * 8;
            #pragma unroll
            for (int e = 0; e < 8; ++e) out[e] = (f16)src[row * 64 + k0 + e];
            *(f16x8*)&wf[f * 512 + l * 8] = out;
        } else if (f < 88) {
            // combined GNN layer-1 frag: K cols 0-7 = [W1a+W1b | b1] (x_src),
            // cols 8-15 = [-W1b | 0] (x_dst), cols 16-31 = 0. Tiles mt=0..3.
            const int mt = f - F_GNN;
            if (mt < 4) {
                const int row = mt * 16 + lr;
                if (g == 0) {
                    #pragma unroll
                    for (int e = 0; e < 8; ++e) {
                        float v = (e < 7) ? (gw1[row * 14 + e] + gw1[row * 14 + 7 + e])
                                          : gb1[row];
                        out[e] = (f16)v;
                    }
                } else if (g == 1) {
                    #pragma unroll
                    for (int e = 0; e < 8; ++e) {
                        float v = (e < 7) ? -gw1[row * 14 + 7 + e] : 0.f;
                        out[e] = (f16)v;
                    }
                }
            }
            *(f16x8*)&wf[f * 512 + l * 8] = out;
        } else {
            const int fb = f - 88, nt = fb >> 1, s = fb & 1;
            const int row = nt * 16 + lr, k0 = s * 32 + g * 8;
            #pragma unroll
            for (int e = 0; e < 8; ++e) out[e] = (f16)gw2[row * 64 + k0 + e];
            *(f16x8*)&wf[W2_ELEM + fb * 512 + l * 8] = out;
        }
    } else if (i < 92 * 64 + 36 * 64) {
        const int e = i - 92 * 64;
        const int tt = e >> 6, l = e & 63;
        unsigned val = 0u;
        if (l < 16) {
            const int r16 = l;
            float c0 = 0.f, c1 = 0.f;
            if (tt < 8)       { int row = tt*16 + r16;            c0 = w0i[row]; c1 = b0i[row] + b0h[row]; }
            else if (tt < 12) { int row = 128 + (tt-8)*16 + r16;  c0 = w0i[row]; c1 = b0i[row]; }
            else if (tt < 16) { int row = 128 + (tt-12)*16 + r16; c1 = b0h[row]; }
            else if (tt < 24) { int row = (tt-16)*16 + r16;       c1 = b1i[row] + b1h[row]; }
            else if (tt < 28) { int row = 128 + (tt-24)*16 + r16; c1 = b1i[row]; }
            else if (tt < 32) { int row = 128 + (tt-28)*16 + r16; c1 = b1h[row]; }
            else              { int row = (tt-32)*16 + r16;       c1 = o1b[row]; }
            fp16x2_builtin t = __builtin_amdgcn_cvt_pkrtz(c0, c1);
            union { fp16x2_builtin v; unsigned u; } c; c.v = t;
            val = c.u;
        }
        ((unsigned*)((char*)wf + SP64_OFF))[tt * 64 + l] = val;
    } else if (i < 92 * 64 + 36 * 64 + 128) {
        const int idx = i - 92 * 64 - 36 * 64;
        float v;
        if (idx < 32) v = gb2[idx];
        else if (idx < 64) v = gwo[idx - 32];
        else v = o2w[idx - 64];
        float* xf = (float*)((char*)wf + EXTRA_OFF);
        xf[idx] = v;
    }
}

// ---------------- encoder (regular launch) ----------------
__global__ __launch_bounds__(1024, 4)
void enc_kernel(const float* __restrict__ enc_in, const float* __restrict__ o2b,
                const f16* __restrict__ wfrag, float* __restrict__ enc_out,
                uint2* __restrict__ hsb, float* __restrict__ hist,
                f16* __restrict__ xw0)
{
    extern __shared__ char smem[];
    const int tid = threadIdx.x;
    stage_all(smem, wfrag, tid);

    Wctx W;
    W.l = tid & 63;
    const int wid = __builtin_amdgcn_readfirstlane(tid >> 6);
    W.g = W.l >> 4; W.n = W.l & 15;
    W.WL = smem;
    W.SP = (const unsigned*)(smem + SP64_OFF);
    W.XT = (const float*)(smem + L_XT_OFF);
    W.S  = smem + L_SCR_OFF + wid * WAVE_SCR;

    const int node = blockIdx.x * NPB + wid * NPW + W.n;
    const bool valid = node < NN;
    const int ndc = valid ? node : NN - 1;
    const float o2b0 = o2b[0];

    f16x8 h0B[2] = {}, h1B[2] = {};
    uint2 h0p[4] = {}, h1p[4] = {};
    const float* pe = enc_in + (size_t)ndc * TE;
    float y = 0.f;
    for (int t = 0; t < TE; ++t) {
        y = gru16_step(W, pe[t], h0B, h1B, h0p, h1p) + o2b0;
        if (W.g == 0 && valid) enc_out[(size_t)node * TE + t] = y;
    }
    {
        uint2* hb0 = hsb + ((size_t)ndc * 2 + 0) * 16 + W.g * 4;
        uint2* hb1 = hsb + ((size_t)ndc * 2 + 1) * 16 + W.g * 4;
        uint4 a0 = {h0p[0].x, h0p[0].y, h0p[1].x, h0p[1].y};
        uint4 a1 = {h0p[2].x, h0p[2].y, h0p[3].x, h0p[3].y};
        uint4 b0 = {h1p[0].x, h1p[0].y, h1p[1].x, h1p[1].y};
        uint4 b1 = {h1p[2].x, h1p[2].y, h1p[3].x, h1p[3].y};
        if (valid) {
            *(uint4*)&hb0[0] = a0; *(uint4*)&hb0[2] = a1;
            *(uint4*)&hb1[0] = b0; *(uint4*)&hb1[2] = b1;
        }
    }
    float win[7];
    #pragma unroll
    for (int j = 0; j < 6; ++j) win[j] = pe[42 + j];
    win[6] = y;
    if (W.g == 0 && valid) {
        #pragma unroll
        for (int j = 0; j < 7; ++j) hist[(size_t)node * 8 + j] = win[j];
        f16x8 xwv = {};
        #pragma unroll
        for (int j = 0; j < 7; ++j) xwv[j] = (f16)win[j];
        xwv[7] = (f16)1.0f;
        *(f16x8*)&xw0[(size_t)node * 8] = xwv;
    }
}

// ---------------- decoder (cooperative) ----------------
__global__ __launch_bounds__(1024, 4)
void dec_kernel(const int* __restrict__ eidx, const float* __restrict__ ea,
                const float* __restrict__ o2b, const float* __restrict__ oparam,
                const float* __restrict__ lin_w, const float* __restrict__ bo,
                const f16* __restrict__ wfrag, float* __restrict__ dec_out,
                const uint2* __restrict__ hsb, const float* __restrict__ hist,
                f16* __restrict__ xw0, f16* __restrict__ xw1)
{
    extern __shared__ char smem[];
    const int tid = threadIdx.x;
    stage_all(smem, wfrag, tid);

    Wctx W;
    W.l = tid & 63;
    const int wid = __builtin_amdgcn_readfirstlane(tid >> 6);
    W.g = W.l >> 4; W.n = W.l & 15;
    W.WL = smem;
    W.SP = (const unsigned*)(smem + SP64_OFF);
    W.XT = (const float*)(smem + L_XT_OFF);
    W.S  = smem + L_SCR_OFF + wid * WAVE_SCR;

    const f32x4 z4 = {0.f, 0.f, 0.f, 0.f};
    const int g = W.g, n = W.n;
    const int node = blockIdx.x * NPB + wid * NPW + n;
    const bool valid = node < NN;
    const int ndc = valid ? node : NN - 1;

    const float o2b0 = o2b[0];
    const float sv = sigf(oparam[0]);
    const float bo0 = bo[0];

    // persistent per-lane edge constants (eidx/ea constant across steps)
    float eav[DEG];
    int srcoff[DEG];
    #pragma unroll
    for (int k = 0; k < DEG; ++k) {
        eav[k] = ea[(size_t)k * NN + ndc];
        srcoff[k] = eidx[(size_t)k * NN + ndc] * 16;   // 16B xw rows
    }
    float invc, nb0;
    {
        float nr = 0.f;
        #pragma unroll
        for (int kk = 0; kk < 8; ++kk) nr += eav[g * 8 + kk];
        nr += __shfl_xor(nr, 16, 64);
        nr += __shfl_xor(nr, 32, 64);
        invc = (1.f - sv) * lin_w[0] * frcp(nr);
        nb0 = bo0 * nr;
    }

    // restore packed state
    uint2 h0p[4], h1p[4];
    {
        const uint2* hb0 = hsb + ((size_t)ndc * 2 + 0) * 16 + g * 4;
        const uint2* hb1 = hsb + ((size_t)ndc * 2 + 1) * 16 + g * 4;
        #pragma unroll
        for (int nt = 0; nt < 4; ++nt) { h0p[nt] = hb0[nt]; h1p[nt] = hb1[nt]; }
    }

    float win[7];
    #pragma unroll
    for (int j = 0; j < 7; ++j) win[j] = hist[(size_t)ndc * 8 + j];

    for (int t = 0; t < TF; ++t) {
        cooperative_groups::this_grid().sync();
        const char* xwc = (const char*)((t & 1) ? xw1 : xw0);
        f16*        xwn = (t & 1) ? xw0 : xw1;

        // per-step constants from LDS (phase-local VGPRs)
        f16x8 Aw2[2][2];
        #pragma unroll
        for (int nj = 0; nj < 2; ++nj)
            #pragma unroll
            for (int s = 0; s < 2; ++s)
                Aw2[nj][s] = *(const f16x8*)(smem + W2_OFF + (nj * 2 + s) * 1024 + W.l * 16);
        f32x4 b2r0 = *(const f32x4*)(W.XT + 0  + g * 4);
        f32x4 b2r1 = *(const f32x4*)(W.XT + 16 + g * 4);
        f32x4 wor0 = *(const f32x4*)(W.XT + 32 + g * 4);
        f32x4 wor1 = *(const f32x4*)(W.XT + 48 + g * 4);

        // x_dst window for this step (g==1 lanes supply B rows 8-15)
        f16x8 xdst = {};
        if (g == 1) {
            #pragma unroll
            for (int j = 0; j < 7; ++j) xdst[j] = (f16)win[j];
            xdst[7] = (f16)1.0f;
        }

        float S = 0.f;
        auto body = [&](int k, f16x8 xs) {
            f16x8 bfrag = (g == 0) ? xs : xdst;   // zero for g>=2
            // fused layer-1: m1_pre = Wcombo * [x_src; x_dst]
            #pragma unroll
            for (int mt = 0; mt < 4; ++mt) {
                f32x4 mm = mf(ldfrag(W.WL, F_GNN + mt, W.l), bfrag, z4);
                uint2 wv;
                wv.x = pk2(fmaxf(mm[0], 0.f), fmaxf(mm[1], 0.f));
                wv.y = pk2(fmaxf(mm[2], 0.f), fmaxf(mm[3], 0.f));
                *(uint2*)(W.S + n * 128 + ((mt ^ (n & 3)) * 32) + g * 8) = wv;
            }
            f16x8 B0 = *(const f16x8*)(W.S + n * 128 + ((((g >> 1))     ^ (n & 3)) * 32) + (g & 1) * 16);
            f16x8 B1 = *(const f16x8*)(W.S + n * 128 + (((2 + (g >> 1)) ^ (n & 3)) * 32) + (g & 1) * 16);
            f32x4 acc0 = mf(Aw2[0][0], B0, z4); acc0 = mf(Aw2[0][1], B1, acc0);
            f32x4 acc1 = mf(Aw2[1][0], B0, z4); acc1 = mf(Aw2[1][1], B1, acc1);
            float ps = 0.f;
            #pragma unroll
            for (int r = 0; r < 4; ++r)
                ps += fmaxf(acc0[r] + b2r0[r], 0.f) * wor0[r]
                    + fmaxf(acc1[r] + b2r1[r], 0.f) * wor1[r];
            S = fmaf(ps, eav[k], S);
        };

        // 2-ahead rolling prefetch, fully unrolled (no runtime-indexed arrays)
        f16x8 xsA = {}, xsB = {};
        if (g == 0) {
            xsA = *(const f16x8*)(xwc + srcoff[0]);
            xsB = *(const f16x8*)(xwc + srcoff[1]);
        }
        #pragma unroll
        for (int kb = 0; kb < 16; ++kb) {
            f16x8 nA = {}, nB = {};
            if (g == 0 && 2 * kb + 2 < DEG) nA = *(const f16x8*)(xwc + srcoff[2 * kb + 2]);
            if (g == 0 && 2 * kb + 3 < DEG) nB = *(const f16x8*)(xwc + srcoff[2 * kb + 3]);
            body(2 * kb,     xsA);
            body(2 * kb + 1, xsB);
            xsA = nA; xsB = nB;
        }
        S += __shfl_xor(S, 16, 64);
        S += __shfl_xor(S, 32, 64);
        const float aggT = S + nb0;

        float y = gru16_step_p(W, win[6], h0p, h1p) + o2b0;
        float o = sv * y + aggT * invc;
        if (g == 0 && valid) dec_out[(size_t)node * TF + t] = o;
        #pragma unroll
        for (int j = 0; j < 6; ++j) win[j] = win[j + 1];
        win[6] = o;
        if (t < TF - 1 && g == 0 && valid) {
            f16x8 xwv = {};
            #pragma unroll
            for (int j = 0; j < 7; ++j) xwv[j] = (f16)win[j];
            xwv[7] = (f16)1.0f;
            *(f16x8*)&xwn[(size_t)node * 8] = xwv;
        }
    }
}

extern "C" void kernel_launch(void* const* d_in, const int* in_sizes, int n_in,
                              void* d_out, int out_size, void* d_ws, size_t ws_size,
                              hipStream_t stream)
{
    const float* enc_in = (const float*)d_in[0];
    const float* ea     = (const float*)d_in[1];
    const int*   eidx   = (const int*)d_in[2];
    const float* w0i = (const float*)d_in[3];
    const float* w0h = (const float*)d_in[4];
    const float* b0i = (const float*)d_in[5];
    const float* b0h = (const float*)d_in[6];
    const float* w1i = (const float*)d_in[7];
    const float* w1h = (const float*)d_in[8];
    const float* b1i = (const float*)d_in[9];
    const float* b1h = (const float*)d_in[10];
    const float* o1w = (const float*)d_in[11];
    const float* o1b = (const float*)d_in[12];
    const float* o2w = (const float*)d_in[13];
    const float* o2b = (const float*)d_in[14];
    const float* gw1  = (const float*)d_in[15];
    const float* gb1  = (const float*)d_in[16];
    const float* gw2  = (const float*)d_in[17];
    const float* gb2  = (const float*)d_in[18];
    const float* gwo  = (const float*)d_in[19];
    const float* gbo  = (const float*)d_in[20];
    const float* glin = (const float*)d_in[21];
    const float* gop  = (const float*)d_in[22];

    float* dec_out = (float*)d_out;                 // [NN][24]
    float* enc_out = dec_out + (size_t)NN * TF;     // [NN][48]

    char* ws = (char*)d_ws;
    f16* wfrag = (f16*)ws;
    char* p = ws + ((GBUF_BYTES + 255) & ~255);
    f16*   xw0  = (f16*)p;    p += (size_t)NN * 8 * 2;   // 800 KB
    f16*   xw1  = (f16*)p;    p += (size_t)NN * 8 * 2;
    uint2* hsb  = (uint2*)p;  p += (size_t)NN * 32 * 8;
    float* hist = (float*)p;  p += (size_t)NN * 8 * 4;

    (void)hipFuncSetAttribute((const void*)enc_kernel,
        hipFuncAttributeMaxDynamicSharedMemorySize, LDS_TOTAL);
    (void)hipFuncSetAttribute((const void*)dec_kernel,
        hipFuncAttributeMaxDynamicSharedMemorySize, LDS_TOTAL);

    pack_weights<<<33, 256, 0, stream>>>(w0i, w0h, b0i, b0h, w1i, w1h, b1i, b1h,
                                         o1w, o1b, gw1, gb1, gw2, gb2, gwo, o2w, wfrag);

    enc_kernel<<<NBLK, 1024, LDS_TOTAL, stream>>>(enc_in, o2b, wfrag, enc_out,
                                                  hsb, hist, xw0);

    void* args[] = {
        (void*)&eidx, (void*)&ea, (void*)&o2b, (void*)&gop, (void*)&glin, (void*)&gbo,
        (void*)&wfrag, (void*)&dec_out, (void*)&hsb, (void*)&hist,
        (void*)&xw0, (void*)&xw1
    };
    (void)hipLaunchCooperativeKernel((const void*)dec_kernel, dim3(NBLK), dim3(1024),
                                     args, LDS_TOTAL, stream);
}

// Round 15
// 2054.722 us; speedup vs baseline: 1.8198x; 1.8198x over previous
//
#include <hip/hip_runtime.h>
#include <hip/hip_cooperative_groups.h>

#define NN 50000
#define TE 48
#define TF 24
#define DEG 32
#define NW 16            // waves per block
#define NPW 16           // nodes per wave
#define NPB 256          // nodes per block
#define NBLK 196         // 196*256 = 50176 >= 50000; co-resident (1 block/CU)

// packed global weight buffer (bytes)
#define F_W0H 0
#define F_W1I 24
#define F_W1H 48
#define F_O1W 72
#define F_GNN 80
#define DENSE_BYTES (88*1024)                 // 90112
#define SP64_OFF DENSE_BYTES
#define SP64_BYTES (36*64*4)                  // 9216
#define W2_OFF (SP64_OFF + SP64_BYTES)        // 99328
#define W2_ELEM (W2_OFF/2)
#define EXTRA_OFF (W2_OFF + 4096)             // 103424: f32 b2[32], wo[32], o2w[64]
#define GBUF_BYTES (EXTRA_OFF + 512)          // 103936

// LDS: [0, EXTRA_OFF) = dense + sp64 + W2, then XT, then wave scratch
#define L_XT_OFF EXTRA_OFF                    // 103424
#define L_SCR_OFF (L_XT_OFF + 512)            // 103936
#define WAVE_SCR 2048
#define LDS_TOTAL (L_SCR_OFF + NW*WAVE_SCR)   // 136704

typedef _Float16 f16;
typedef __attribute__((ext_vector_type(8))) _Float16 f16x8;
typedef __attribute__((ext_vector_type(2))) __fp16 fp16x2_builtin;
typedef __attribute__((ext_vector_type(4))) float f32x4;

__device__ __forceinline__ float frcp(float x) { return __builtin_amdgcn_rcpf(x); }
__device__ __forceinline__ float sigf(float x) { return frcp(1.f + __expf(-x)); }
__device__ __forceinline__ float tanhfast(float x) {
    float e = __expf(-2.f * fabsf(x));
    float r = (1.f - e) * frcp(1.f + e);
    return copysignf(r, x);
}
__device__ __forceinline__ f32x4 mf(f16x8 a, f16x8 b, f32x4 c) {
    return __builtin_amdgcn_mfma_f32_16x16x32_f16(a, b, c, 0, 0, 0);
}
__device__ __forceinline__ f16x8 ldfrag(const char* L, int f, int l) {
    return *(const f16x8*)(L + f * 1024 + l * 16);
}
__device__ __forceinline__ f16x8 spfrag64(const unsigned* sp, int tt, int l) {
    unsigned d = sp[tt * 64 + l];     // zero for lanes >=16 (table padded)
    union { unsigned u; f16 h[2]; } c; c.u = d;
    f16x8 r = {};
    r[0] = c.h[0]; r[1] = c.h[1];
    return r;
}
__device__ __forceinline__ unsigned pk2(float a, float b) {
    fp16x2_builtin t = __builtin_amdgcn_cvt_pkrtz(a, b);
    union { fp16x2_builtin v; unsigned u; } c; c.v = t; return c.u;
}
__device__ __forceinline__ void upk2(unsigned u, float& a, float& b) {
    union { unsigned uu; f16 h[2]; } c; c.uu = u;
    a = (float)c.h[0]; b = (float)c.h[1];
}

struct Wctx {
    int l, g, n;
    char* S;
    const char* WL;
    const unsigned* SP;
    const float* XT;
};

// packed h (uint2[4], D-layout) -> B-frag via wave-internal LDS scratch
__device__ __forceinline__ void transp(const Wctx& W, const uint2 (&hp)[4], f16x8 (&hB)[2]) {
    #pragma unroll
    for (int nt = 0; nt < 4; ++nt)
        *(uint2*)(W.S + W.n * 128 + (((2 * nt + (W.g >> 1)) ^ (W.n & 7)) * 16) + 8 * (W.g & 1)) = hp[nt];
    #pragma unroll
    for (int s = 0; s < 2; ++s)
        hB[s] = *(const f16x8*)(W.S + W.n * 128 + (((4 * s + W.g) ^ (W.n & 7)) * 16));
}

// ---- GRU sub-phases ----
__device__ __forceinline__ void gru_l0(const Wctx& W, f16x8 xb,
    const f16x8 (&h0B)[2], uint2 (&h0p)[4])
{
    const f32x4 z4 = {0.f, 0.f, 0.f, 0.f};
    const int l = W.l;
    #pragma unroll
    for (int nt = 0; nt < 4; ++nt) {
        f32x4 aR = mf(spfrag64(W.SP, nt, l), xb, z4);
        aR = mf(ldfrag(W.WL, F_W0H + nt * 2,     l), h0B[0], aR);
        aR = mf(ldfrag(W.WL, F_W0H + nt * 2 + 1, l), h0B[1], aR);
        f32x4 aZ = mf(spfrag64(W.SP, 4 + nt, l), xb, z4);
        aZ = mf(ldfrag(W.WL, F_W0H + (4 + nt) * 2,     l), h0B[0], aZ);
        aZ = mf(ldfrag(W.WL, F_W0H + (4 + nt) * 2 + 1, l), h0B[1], aZ);
        f32x4 aNi = mf(spfrag64(W.SP, 8 + nt, l), xb, z4);
        f32x4 aNh = mf(spfrag64(W.SP, 12 + nt, l), xb, z4);
        aNh = mf(ldfrag(W.WL, F_W0H + (8 + nt) * 2,     l), h0B[0], aNh);
        aNh = mf(ldfrag(W.WL, F_W0H + (8 + nt) * 2 + 1, l), h0B[1], aNh);
        float ho[4], hn[4];
        upk2(h0p[nt].x, ho[0], ho[1]);
        upk2(h0p[nt].y, ho[2], ho[3]);
        #pragma unroll
        for (int r = 0; r < 4; ++r) {
            float rg = sigf(aR[r]);
            float zg = sigf(aZ[r]);
            float ng = tanhfast(aNi[r] + rg * aNh[r]);
            hn[r] = ng + zg * (ho[r] - ng);
        }
        h0p[nt].x = pk2(hn[0], hn[1]);
        h0p[nt].y = pk2(hn[2], hn[3]);
    }
}

template<int NT0, int NT1>
__device__ __forceinline__ void gru_l1(const Wctx& W, f16x8 xb,
    const f16x8 (&h0B)[2], const f16x8 (&h1B)[2], uint2 (&h1p)[4])
{
    const f32x4 z4 = {0.f, 0.f, 0.f, 0.f};
    const int l = W.l;
    #pragma unroll
    for (int nt = NT0; nt < NT1; ++nt) {
        f32x4 aRa = mf(spfrag64(W.SP, 16 + nt, l), xb, z4);
        aRa = mf(ldfrag(W.WL, F_W1I + nt * 2,     l), h0B[0], aRa);
        aRa = mf(ldfrag(W.WL, F_W1I + nt * 2 + 1, l), h0B[1], aRa);
        f32x4 aRb = mf(ldfrag(W.WL, F_W1H + nt * 2, l), h1B[0], z4);
        aRb = mf(ldfrag(W.WL, F_W1H + nt * 2 + 1,   l), h1B[1], aRb);
        f32x4 aZa = mf(spfrag64(W.SP, 20 + nt, l), xb, z4);
        aZa = mf(ldfrag(W.WL, F_W1I + (4 + nt) * 2,     l), h0B[0], aZa);
        aZa = mf(ldfrag(W.WL, F_W1I + (4 + nt) * 2 + 1, l), h0B[1], aZa);
        f32x4 aZb = mf(ldfrag(W.WL, F_W1H + (4 + nt) * 2, l), h1B[0], z4);
        aZb = mf(ldfrag(W.WL, F_W1H + (4 + nt) * 2 + 1,   l), h1B[1], aZb);
        f32x4 aNi = mf(spfrag64(W.SP, 24 + nt, l), xb, z4);
        aNi = mf(ldfrag(W.WL, F_W1I + (8 + nt) * 2,     l), h0B[0], aNi);
        aNi = mf(ldfrag(W.WL, F_W1I + (8 + nt) * 2 + 1, l), h0B[1], aNi);
        f32x4 aNh = mf(spfrag64(W.SP, 28 + nt, l), xb, z4);
        aNh = mf(ldfrag(W.WL, F_W1H + (8 + nt) * 2,     l), h1B[0], aNh);
        aNh = mf(ldfrag(W.WL, F_W1H + (8 + nt) * 2 + 1, l), h1B[1], aNh);
        float ho[4], hn[4];
        upk2(h1p[nt].x, ho[0], ho[1]);
        upk2(h1p[nt].y, ho[2], ho[3]);
        #pragma unroll
        for (int r = 0; r < 4; ++r) {
            float rg = sigf(aRa[r] + aRb[r]);
            float zg = sigf(aZa[r] + aZb[r]);
            float ng = tanhfast(aNi[r] + rg * aNh[r]);
            hn[r] = ng + zg * (ho[r] - ng);
        }
        h1p[nt].x = pk2(hn[0], hn[1]);
        h1p[nt].y = pk2(hn[2], hn[3]);
    }
}

__device__ __forceinline__ float gru_head(const Wctx& W, f16x8 xb, const f16x8 (&h1B)[2])
{
    const f32x4 z4 = {0.f, 0.f, 0.f, 0.f};
    const int l = W.l;
    float y = 0.f;
    #pragma unroll
    for (int nt = 0; nt < 4; ++nt) {
        f32x4 aH = mf(spfrag64(W.SP, 32 + nt, l), xb, z4);
        aH = mf(ldfrag(W.WL, F_O1W + nt * 2,     l), h1B[0], aH);
        aH = mf(ldfrag(W.WL, F_O1W + nt * 2 + 1, l), h1B[1], aH);
        f32x4 ow = *(const f32x4*)(W.XT + 64 + nt * 16 + W.g * 4);
        #pragma unroll
        for (int r = 0; r < 4; ++r)
            y += fmaxf(aH[r], 0.f) * ow[r];
    }
    y += __shfl_xor(y, 16, 64);
    y += __shfl_xor(y, 32, 64);
    return y;
}

// monolithic step
__device__ __forceinline__ float gru16_step(const Wctx& W, float x,
    f16x8 (&h0B)[2], f16x8 (&h1B)[2], uint2 (&h0p)[4], uint2 (&h1p)[4])
{
    f16x8 xb = {};
    if (W.g == 0) { xb[0] = (f16)x; xb[1] = (f16)1.0f; }
    gru_l0(W, xb, h0B, h0p);
    transp(W, h0p, h0B);
    gru_l1<0, 4>(W, xb, h0B, h1B, h1p);
    transp(W, h1p, h1B);
    return gru_head(W, xb, h1B);
}

__device__ __forceinline__ float gru16_step_p(const Wctx& W, float x,
    uint2 (&h0p)[4], uint2 (&h1p)[4])
{
    f16x8 h0B[2], h1B[2];
    transp(W, h0p, h0B);
    transp(W, h1p, h1B);
    return gru16_step(W, x, h0B, h1B, h0p, h1p);
}

// GNN projection: x7 -> u (fp8 packed to global, [node][g][16B]) + v (f32 regs)
__device__ __forceinline__ void project_uv(const Wctx& W, const float (&win)[7],
    bool valid, int node, char* __restrict__ ubw, float (&vf)[16])
{
    const f32x4 z4 = {0.f, 0.f, 0.f, 0.f};
    const int g = W.g, n = W.n;
    f16x8 xw = {};
    if (g == 0) {
        #pragma unroll
        for (int j = 0; j < 7; ++j) xw[j] = (f16)win[j];
        xw[7] = (f16)1.0f;
    }
    #pragma unroll
    for (int mt = 0; mt < 4; ++mt) {
        f32x4 a = mf(ldfrag(W.WL, F_GNN + mt, W.l), xw, z4);
        uint2 wv; wv.x = pk2(a[0], a[1]); wv.y = pk2(a[2], a[3]);
        *(uint2*)(W.S + n * 128 + ((mt ^ (n & 3)) * 32) + g * 8) = wv;
    }
    {
        f16x8 uu0 = *(const f16x8*)(W.S + n * 128 + ((((g >> 1))     ^ (n & 3)) * 32) + (g & 1) * 16);
        f16x8 uu1 = *(const f16x8*)(W.S + n * 128 + (((2 + (g >> 1)) ^ (n & 3)) * 32) + (g & 1) * 16);
        int w0 = __builtin_amdgcn_cvt_pk_fp8_f32((float)uu0[0], (float)uu0[1], 0, false);
        w0     = __builtin_amdgcn_cvt_pk_fp8_f32((float)uu0[2], (float)uu0[3], w0, true);
        int w1 = __builtin_amdgcn_cvt_pk_fp8_f32((float)uu0[4], (float)uu0[5], 0, false);
        w1     = __builtin_amdgcn_cvt_pk_fp8_f32((float)uu0[6], (float)uu0[7], w1, true);
        int w2 = __builtin_amdgcn_cvt_pk_fp8_f32((float)uu1[0], (float)uu1[1], 0, false);
        w2     = __builtin_amdgcn_cvt_pk_fp8_f32((float)uu1[2], (float)uu1[3], w2, true);
        int w3 = __builtin_amdgcn_cvt_pk_fp8_f32((float)uu1[4], (float)uu1[5], 0, false);
        w3     = __builtin_amdgcn_cvt_pk_fp8_f32((float)uu1[6], (float)uu1[7], w3, true);
        uint4 pk;
        pk.x = (unsigned)w0; pk.y = (unsigned)w1; pk.z = (unsigned)w2; pk.w = (unsigned)w3;
        if (valid) *(uint4*)(ubw + (size_t)node * 64 + g * 16) = pk;
    }
    #pragma unroll
    for (int mt = 0; mt < 4; ++mt) {
        f32x4 a = mf(ldfrag(W.WL, F_GNN + 4 + mt, W.l), xw, z4);
        uint2 wv; wv.x = pk2(a[0], a[1]); wv.y = pk2(a[2], a[3]);
        *(uint2*)(W.S + n * 128 + ((mt ^ (n & 3)) * 32) + g * 8) = wv;
    }
    {
        f16x8 v0 = *(const f16x8*)(W.S + n * 128 + ((((g >> 1))     ^ (n & 3)) * 32) + (g & 1) * 16);
        f16x8 v1 = *(const f16x8*)(W.S + n * 128 + (((2 + (g >> 1)) ^ (n & 3)) * 32) + (g & 1) * 16);
        #pragma unroll
        for (int e = 0; e < 8; ++e) {
            vf[e]     = (float)v0[e];
            vf[8 + e] = (float)v1[e];
        }
    }
}

__device__ __forceinline__ void stage_all(char* smem, const f16* wfrag, int tid) {
    uint4* d = (uint4*)smem;
    const uint4* s4 = (const uint4*)wfrag;
    for (int i = tid; i < EXTRA_OFF / 16; i += 1024) d[i] = s4[i];
    if (tid < 32) {
        uint4* de = (uint4*)(smem + L_XT_OFF);
        const uint4* se = (const uint4*)((const char*)wfrag + EXTRA_OFF);
        de[tid] = se[tid];
    }
    __syncthreads();
}

// ---------------- weight packing ----------------
__global__ __launch_bounds__(256)
void pack_weights(const float* __restrict__ w0i, const float* __restrict__ w0h,
                  const float* __restrict__ b0i, const float* __restrict__ b0h,
                  const float* __restrict__ w1i, const float* __restrict__ w1h,
                  const float* __restrict__ b1i, const float* __restrict__ b1h,
                  const float* __restrict__ o1w, const float* __restrict__ o1b,
                  const float* __restrict__ gw1, const float* __restrict__ gb1,
                  const float* __restrict__ gw2, const float* __restrict__ gb2,
                  const float* __restrict__ gwo, const float* __restrict__ o2w,
                  f16* __restrict__ wf)
{
    const int i = blockIdx.x * 256 + threadIdx.x;
    if (i < 92 * 64) {
        const int f = i >> 6, l = i & 63;
        const int lr = l & 15, g = l >> 4;
        f16x8 out = {};
        if (f < F_GNN) {
            const float* src; int fb;
            if (f < F_W1I)      { src = w0h; fb = f; }
            else if (f < F_W1H) { src = w1i; fb = f - F_W1I; }
            else if (f < F_O1W) { src = w1h; fb = f - F_W1H; }
            else                { src = o1w; fb = f - F_O1W; }
            const int nt = fb >> 1, s = fb & 1;
            const int row = nt * 16 + lr, k0 = s * 32 + g * 8;
            #pragma unroll
            for (int e = 0; e < 8; ++e) out[e] = (f16)src[row * 64 + k0 + e];
            *(f16x8*)&wf[f * 512 + l * 8] = out;
        } else if (f < 88) {
            const int mt = f - F_GNN;
            const int m = mt * 16 + lr;
            #pragma unroll
            for (int e = 0; e < 8; ++e) {
                int k = g * 8 + e; float v = 0.f;
                if (m < 64) {
                    if (k < 7) v = gw1[m * 14 + k] + gw1[m * 14 + 7 + k];
                    else if (k == 7) v = gb1[m];
                } else {
                    int mm = m - 64;
                    if (k < 7) v = -gw1[mm * 14 + 7 + k];
                }
                out[e] = (f16)v;
            }
            *(f16x8*)&wf[f * 512 + l * 8] = out;
        } else {
            const int fb = f - 88, nt = fb >> 1, s = fb & 1;
            const int row = nt * 16 + lr, k0 = s * 32 + g * 8;
            #pragma unroll
            for (int e = 0; e < 8; ++e) out[e] = (f16)gw2[row * 64 + k0 + e];
            *(f16x8*)&wf[W2_ELEM + fb * 512 + l * 8] = out;
        }
    } else if (i < 92 * 64 + 36 * 64) {
        const int e = i - 92 * 64;
        const int tt = e >> 6, l = e & 63;
        unsigned val = 0u;
        if (l < 16) {
            const int r16 = l;
            float c0 = 0.f, c1 = 0.f;
            if (tt < 8)       { int row = tt*16 + r16;            c0 = w0i[row]; c1 = b0i[row] + b0h[row]; }
            else if (tt < 12) { int row = 128 + (tt-8)*16 + r16;  c0 = w0i[row]; c1 = b0i[row]; }
            else if (tt < 16) { int row = 128 + (tt-12)*16 + r16; c1 = b0h[row]; }
            else if (tt < 24) { int row = (tt-16)*16 + r16;       c1 = b1i[row] + b1h[row]; }
            else if (tt < 28) { int row = 128 + (tt-24)*16 + r16; c1 = b1i[row]; }
            else if (tt < 32) { int row = 128 + (tt-28)*16 + r16; c1 = b1h[row]; }
            else              { int row = (tt-32)*16 + r16;       c1 = o1b[row]; }
            fp16x2_builtin t = __builtin_amdgcn_cvt_pkrtz(c0, c1);
            union { fp16x2_builtin v; unsigned u; } c; c.v = t;
            val = c.u;
        }
        ((unsigned*)((char*)wf + SP64_OFF))[tt * 64 + l] = val;
    } else if (i < 92 * 64 + 36 * 64 + 128) {
        const int idx = i - 92 * 64 - 36 * 64;
        float v;
        if (idx < 32) v = gb2[idx];
        else if (idx < 64) v = gwo[idx - 32];
        else v = o2w[idx - 64];
        float* xf = (float*)((char*)wf + EXTRA_OFF);
        xf[idx] = v;
    }
}

// ---------------- encoder (regular launch) ----------------
__attribute__((amdgpu_waves_per_eu(4, 4)))
__global__ __launch_bounds__(1024)
void enc_kernel(const float* __restrict__ enc_in, const float* __restrict__ o2b,
                const f16* __restrict__ wfrag, float* __restrict__ enc_out,
                uint2* __restrict__ hsb, float* __restrict__ hist,
                char* __restrict__ ub0)
{
    extern __shared__ char smem[];
    const int tid = threadIdx.x;
    stage_all(smem, wfrag, tid);

    Wctx W;
    W.l = tid & 63;
    const int wid = __builtin_amdgcn_readfirstlane(tid >> 6);
    W.g = W.l >> 4; W.n = W.l & 15;
    W.WL = smem;
    W.SP = (const unsigned*)(smem + SP64_OFF);
    W.XT = (const float*)(smem + L_XT_OFF);
    W.S  = smem + L_SCR_OFF + wid * WAVE_SCR;

    const int node = blockIdx.x * NPB + wid * NPW + W.n;
    const bool valid = node < NN;
    const int ndc = valid ? node : NN - 1;
    const float o2b0 = o2b[0];

    f16x8 h0B[2] = {}, h1B[2] = {};
    uint2 h0p[4] = {}, h1p[4] = {};
    const float* pe = enc_in + (size_t)ndc * TE;
    float y = 0.f;
    for (int t = 0; t < TE; ++t) {
        y = gru16_step(W, pe[t], h0B, h1B, h0p, h1p) + o2b0;
        if (W.g == 0 && valid) enc_out[(size_t)node * TE + t] = y;
    }
    {
        uint2* hb0 = hsb + ((size_t)ndc * 2 + 0) * 16 + W.g * 4;
        uint2* hb1 = hsb + ((size_t)ndc * 2 + 1) * 16 + W.g * 4;
        uint4 a0 = {h0p[0].x, h0p[0].y, h0p[1].x, h0p[1].y};
        uint4 a1 = {h0p[2].x, h0p[2].y, h0p[3].x, h0p[3].y};
        uint4 b0 = {h1p[0].x, h1p[0].y, h1p[1].x, h1p[1].y};
        uint4 b1 = {h1p[2].x, h1p[2].y, h1p[3].x, h1p[3].y};
        if (valid) {
            *(uint4*)&hb0[0] = a0; *(uint4*)&hb0[2] = a1;
            *(uint4*)&hb1[0] = b0; *(uint4*)&hb1[2] = b1;
        }
    }
    float win[7];
    #pragma unroll
    for (int j = 0; j < 6; ++j) win[j] = pe[42 + j];
    win[6] = y;
    if (W.g == 0 && valid) {
        #pragma unroll
        for (int j = 0; j < 7; ++j) hist[(size_t)node * 8 + j] = win[j];
    }
    float vf[16];
    project_uv(W, win, valid, node, ub0, vf);
}

// ---------------- decoder (cooperative) ----------------
__attribute__((amdgpu_waves_per_eu(3, 4)))
__global__ __launch_bounds__(1024)
void dec_kernel(const int* __restrict__ eidx, const float* __restrict__ ea,
                const float* __restrict__ o2b, const float* __restrict__ oparam,
                const float* __restrict__ lin_w, const float* __restrict__ bo,
                const f16* __restrict__ wfrag, float* __restrict__ dec_out,
                const uint2* __restrict__ hsb, const float* __restrict__ hist,
                char* __restrict__ ub0, char* __restrict__ ub1)
{
    extern __shared__ char smem[];
    const int tid = threadIdx.x;
    stage_all(smem, wfrag, tid);

    Wctx W;
    W.l = tid & 63;
    const int wid = __builtin_amdgcn_readfirstlane(tid >> 6);
    W.g = W.l >> 4; W.n = W.l & 15;
    W.WL = smem;
    W.SP = (const unsigned*)(smem + SP64_OFF);
    W.XT = (const float*)(smem + L_XT_OFF);
    W.S  = smem + L_SCR_OFF + wid * WAVE_SCR;

    const f32x4 z4 = {0.f, 0.f, 0.f, 0.f};
    const int g = W.g;
    const int node = blockIdx.x * NPB + wid * NPW + W.n;
    const bool valid = node < NN;
    const int ndc = valid ? node : NN - 1;

    const float o2b0 = o2b[0];
    const float sv = sigf(oparam[0]);
    const float bo0 = bo[0];

    // persistent per-lane edge constants (eidx/ea constant across steps)
    float eav[DEG];
    int srcoff[DEG];
    #pragma unroll
    for (int k = 0; k < DEG; ++k) {
        eav[k] = ea[(size_t)k * NN + ndc];
        srcoff[k] = eidx[(size_t)k * NN + ndc] * 64 + g * 16;
    }
    float invc, nb0;
    {
        float nr = 0.f;
        #pragma unroll
        for (int kk = 0; kk < 8; ++kk) nr += eav[g * 8 + kk];
        nr += __shfl_xor(nr, 16, 64);
        nr += __shfl_xor(nr, 32, 64);
        invc = (1.f - sv) * lin_w[0] * frcp(nr);
        nb0 = bo0 * nr;
    }

    // restore packed state
    uint2 h0p[4], h1p[4];
    {
        const uint2* hb0 = hsb + ((size_t)ndc * 2 + 0) * 16 + g * 4;
        const uint2* hb1 = hsb + ((size_t)ndc * 2 + 1) * 16 + g * 4;
        #pragma unroll
        for (int nt = 0; nt < 4; ++nt) { h0p[nt] = hb0[nt]; h1p[nt] = hb1[nt]; }
    }

    float win[7];
    #pragma unroll
    for (int j = 0; j < 7; ++j) win[j] = (g == 0) ? hist[(size_t)ndc * 8 + j] : 0.f;

    float vf[16];
    project_uv(W, win, valid, node, ub0, vf);

    for (int t = 0; t < TF; ++t) {
        cooperative_groups::this_grid().sync();
        const char* ub = (t & 1) ? ub1 : ub0;
        char*      ubw = (t & 1) ? ub0 : ub1;

        // per-step constants from LDS (phase-local VGPRs)
        f16x8 Aw2[2][2];
        #pragma unroll
        for (int nj = 0; nj < 2; ++nj)
            #pragma unroll
            for (int s = 0; s < 2; ++s)
                Aw2[nj][s] = *(const f16x8*)(smem + W2_OFF + (nj * 2 + s) * 1024 + W.l * 16);
        f32x4 b2r0 = *(const f32x4*)(W.XT + 0  + g * 4);
        f32x4 b2r1 = *(const f32x4*)(W.XT + 16 + g * 4);
        f32x4 wor0 = *(const f32x4*)(W.XT + 32 + g * 4);
        f32x4 wor1 = *(const f32x4*)(W.XT + 48 + g * 4);

        float S = 0.f;
        #pragma unroll
        for (int k = 0; k < DEG; ++k) {
            uint4 U = *(const uint4*)(ub + srcoff[k]);
            unsigned wd[4];
            wd[0] = U.x; wd[1] = U.y; wd[2] = U.z; wd[3] = U.w;
            unsigned mw[8];
            #pragma unroll
            for (int c = 0; c < 4; ++c) {
                auto a = __builtin_amdgcn_cvt_pk_f32_fp8((int)wd[c], false);
                auto b = __builtin_amdgcn_cvt_pk_f32_fp8((int)wd[c], true);
                float e0 = fmaxf(a[0] + vf[c * 4 + 0], 0.f);
                float e1 = fmaxf(a[1] + vf[c * 4 + 1], 0.f);
                float e2 = fmaxf(b[0] + vf[c * 4 + 2], 0.f);
                float e3 = fmaxf(b[1] + vf[c * 4 + 3], 0.f);
                mw[c * 2]     = pk2(e0, e1);
                mw[c * 2 + 1] = pk2(e2, e3);
            }
            union { uint4 u; f16x8 h; } M0, M1;
            M0.u.x = mw[0]; M0.u.y = mw[1]; M0.u.z = mw[2]; M0.u.w = mw[3];
            M1.u.x = mw[4]; M1.u.y = mw[5]; M1.u.z = mw[6]; M1.u.w = mw[7];
            f32x4 acc0 = mf(Aw2[0][0], M0.h, z4); acc0 = mf(Aw2[0][1], M1.h, acc0);
            f32x4 acc1 = mf(Aw2[1][0], M0.h, z4); acc1 = mf(Aw2[1][1], M1.h, acc1);
            float ps = 0.f;
            #pragma unroll
            for (int r = 0; r < 4; ++r)
                ps += fmaxf(acc0[r] + b2r0[r], 0.f) * wor0[r]
                    + fmaxf(acc1[r] + b2r1[r], 0.f) * wor1[r];
            S = fmaf(ps, eav[k], S);
        }
        S += __shfl_xor(S, 16, 64);
        S += __shfl_xor(S, 32, 64);
        const float aggT = S + nb0;

        float y = gru16_step_p(W, win[6], h0p, h1p) + o2b0;
        float o = sv * y + aggT * invc;
        if (g == 0 && valid) dec_out[(size_t)node * TF + t] = o;
        #pragma unroll
        for (int j = 0; j < 6; ++j) win[j] = win[j + 1];
        win[6] = o;
        if (t < TF - 1) project_uv(W, win, valid, node, ubw, vf);
    }
}

extern "C" void kernel_launch(void* const* d_in, const int* in_sizes, int n_in,
                              void* d_out, int out_size, void* d_ws, size_t ws_size,
                              hipStream_t stream)
{
    const float* enc_in = (const float*)d_in[0];
    const float* ea     = (const float*)d_in[1];
    const int*   eidx   = (const int*)d_in[2];
    const float* w0i = (const float*)d_in[3];
    const float* w0h = (const float*)d_in[4];
    const float* b0i = (const float*)d_in[5];
    const float* b0h = (const float*)d_in[6];
    const float* w1i = (const float*)d_in[7];
    const float* w1h = (const float*)d_in[8];
    const float* b1i = (const float*)d_in[9];
    const float* b1h = (const float*)d_in[10];
    const float* o1w = (const float*)d_in[11];
    const float* o1b = (const float*)d_in[12];
    const float* o2w = (const float*)d_in[13];
    const float* o2b = (const float*)d_in[14];
    const float* gw1  = (const float*)d_in[15];
    const float* gb1  = (const float*)d_in[16];
    const float* gw2  = (const float*)d_in[17];
    const float* gb2  = (const float*)d_in[18];
    const float* gwo  = (const float*)d_in[19];
    const float* gbo  = (const float*)d_in[20];
    const float* glin = (const float*)d_in[21];
    const float* gop  = (const float*)d_in[22];

    float* dec_out = (float*)d_out;                 // [NN][24]
    float* enc_out = dec_out + (size_t)NN * TF;     // [NN][48]

    char* ws = (char*)d_ws;
    f16* wfrag = (f16*)ws;
    char* p = ws + ((GBUF_BYTES + 255) & ~255);
    char*  ub0  = p;          p += (size_t)NN * 64;   // fp8 u rows (3.2 MB)
    char*  ub1  = p;          p += (size_t)NN * 64;
    uint2* hsb  = (uint2*)p;  p += (size_t)NN * 32 * 8;
    float* hist = (float*)p;  p += (size_t)NN * 8 * 4;

    (void)hipFuncSetAttribute((const void*)enc_kernel,
        hipFuncAttributeMaxDynamicSharedMemorySize, LDS_TOTAL);
    (void)hipFuncSetAttribute((const void*)dec_kernel,
        hipFuncAttributeMaxDynamicSharedMemorySize, LDS_TOTAL);

    pack_weights<<<33, 256, 0, stream>>>(w0i, w0h, b0i, b0h, w1i, w1h, b1i, b1h,
                                         o1w, o1b, gw1, gb1, gw2, gb2, gwo, o2w, wfrag);

    enc_kernel<<<NBLK, 1024, LDS_TOTAL, stream>>>(enc_in, o2b, wfrag, enc_out,
                                                  hsb, hist, ub0);

    void* args[] = {
        (void*)&eidx, (void*)&ea, (void*)&o2b, (void*)&gop, (void*)&glin, (void*)&gbo,
        (void*)&wfrag, (void*)&dec_out, (void*)&hsb, (void*)&hist,
        (void*)&ub0, (void*)&ub1
    };
    (void)hipLaunchCooperativeKernel((const void*)dec_kernel, dim3(NBLK), dim3(1024),
                                     args, LDS_TOTAL, stream);
}